// Round 1
// baseline (1168.759 us; speedup 1.0000x reference)
//
#include <hip/hip_runtime.h>
#include <math.h>

// GatedGCN forward, fp32. D = U = 96 hard-coded.
// newX = X@Wn+bn ; agg = scatter_add(a * newX[col] -> row)
// gate = sigmoid(X@Wgi + agg@Wgn + bgi + bgn) ; out = agg*gate + X*(1-gate)

#define DU 96
#define DU4 24  // DU/4 float4 chunks per row

// ---------------- Kernel A: newX = X @ Wn + bn ----------------
// 64 rows/block, 256 threads, 4x6 register tile per thread.
__global__ __launch_bounds__(256) void k_newX(const float* __restrict__ X,
                                              const float* __restrict__ W,
                                              const float* __restrict__ b,
                                              float* __restrict__ Y, int N) {
  __shared__ float Xs[64][97];       // +1 pad: row-broadcast reads hit distinct banks
  __shared__ float Ws[DU * DU];
  const int tid = threadIdx.x;
  const int row0 = blockIdx.x * 64;

  for (int i = tid; i < DU * DU; i += 256) Ws[i] = W[i];
  for (int i = tid; i < 64 * DU4; i += 256) {
    int r = i / DU4, c = i % DU4;
    int gr = row0 + r;
    float4 v = make_float4(0.f, 0.f, 0.f, 0.f);
    if (gr < N) v = ((const float4*)X)[gr * DU4 + c];
    Xs[r][4 * c + 0] = v.x;
    Xs[r][4 * c + 1] = v.y;
    Xs[r][4 * c + 2] = v.z;
    Xs[r][4 * c + 3] = v.w;
  }
  __syncthreads();

  const int colg = tid & 15;   // 16 groups x 6 cols
  const int rowg = tid >> 4;   // 16 groups x 4 rows
  float acc[4][6];
#pragma unroll
  for (int r = 0; r < 4; ++r)
#pragma unroll
    for (int j = 0; j < 6; ++j) acc[r][j] = 0.f;

  for (int k = 0; k < DU; ++k) {
    float x0 = Xs[rowg * 4 + 0][k];
    float x1 = Xs[rowg * 4 + 1][k];
    float x2 = Xs[rowg * 4 + 2][k];
    float x3 = Xs[rowg * 4 + 3][k];
    const float* wr = &Ws[k * DU + colg * 6];
#pragma unroll
    for (int j = 0; j < 6; ++j) {
      float w = wr[j];
      acc[0][j] = fmaf(x0, w, acc[0][j]);
      acc[1][j] = fmaf(x1, w, acc[1][j]);
      acc[2][j] = fmaf(x2, w, acc[2][j]);
      acc[3][j] = fmaf(x3, w, acc[3][j]);
    }
  }

#pragma unroll
  for (int r = 0; r < 4; ++r) {
    int gr = row0 + rowg * 4 + r;
    if (gr < N) {
      float* yp = Y + gr * DU + colg * 6;
#pragma unroll
      for (int j = 0; j < 6; ++j) yp[j] = acc[r][j] + b[colg * 6 + j];
    }
  }
}

// ---------------- Kernel B: scatter-add messages ----------------
// One thread per (edge, float4-chunk): 24 chunk-threads per edge.
__global__ __launch_bounds__(256) void k_scatter(const float* __restrict__ newX,
                                                 const float* __restrict__ a_vals,
                                                 const int* __restrict__ row,
                                                 const int* __restrict__ col,
                                                 float* __restrict__ agg, int E) {
  int i = blockIdx.x * 256 + threadIdx.x;
  if (i >= E * DU4) return;
  int e = i / DU4;
  int c = i % DU4;
  int s = col[e];
  int d = row[e];
  float a = a_vals[e];
  float4 v = ((const float4*)newX)[s * DU4 + c];
  float* dst = agg + d * DU + c * 4;
  atomicAdd(dst + 0, v.x * a);
  atomicAdd(dst + 1, v.y * a);
  atomicAdd(dst + 2, v.z * a);
  atomicAdd(dst + 3, v.w * a);
}

// ---------------- Kernel C: gate + residual combine ----------------
// 32 rows/block, 256 threads, 2x6 tile; two phases share one LDS W buffer.
__global__ __launch_bounds__(256) void k_gate(const float* __restrict__ X,
                                              const float* __restrict__ A,
                                              const float* __restrict__ Wgi,
                                              const float* __restrict__ Wgn,
                                              const float* __restrict__ bgi,
                                              const float* __restrict__ bgn,
                                              float* __restrict__ Out, int N) {
  __shared__ float Xs[32][97];
  __shared__ float As[32][97];
  __shared__ float Ws[DU * DU];
  const int tid = threadIdx.x;
  const int row0 = blockIdx.x * 32;

  for (int i = tid; i < 32 * DU4; i += 256) {
    int r = i / DU4, c = i % DU4;
    int gr = row0 + r;
    float4 vx = make_float4(0.f, 0.f, 0.f, 0.f);
    float4 va = make_float4(0.f, 0.f, 0.f, 0.f);
    if (gr < N) {
      vx = ((const float4*)X)[gr * DU4 + c];
      va = ((const float4*)A)[gr * DU4 + c];
    }
    Xs[r][4 * c + 0] = vx.x; Xs[r][4 * c + 1] = vx.y;
    Xs[r][4 * c + 2] = vx.z; Xs[r][4 * c + 3] = vx.w;
    As[r][4 * c + 0] = va.x; As[r][4 * c + 1] = va.y;
    As[r][4 * c + 2] = va.z; As[r][4 * c + 3] = va.w;
  }
  for (int i = tid; i < DU * DU; i += 256) Ws[i] = Wgi[i];
  __syncthreads();

  const int colg = tid & 15;   // 16 x 6 cols
  const int rowg = tid >> 4;   // 16 x 2 rows
  float acc[2][6];
#pragma unroll
  for (int r = 0; r < 2; ++r)
#pragma unroll
    for (int j = 0; j < 6; ++j) acc[r][j] = 0.f;

  // Phase 1: X @ Wgi
  for (int k = 0; k < DU; ++k) {
    float x0 = Xs[rowg * 2 + 0][k];
    float x1 = Xs[rowg * 2 + 1][k];
    const float* wr = &Ws[k * DU + colg * 6];
#pragma unroll
    for (int j = 0; j < 6; ++j) {
      float w = wr[j];
      acc[0][j] = fmaf(x0, w, acc[0][j]);
      acc[1][j] = fmaf(x1, w, acc[1][j]);
    }
  }
  __syncthreads();
  for (int i = tid; i < DU * DU; i += 256) Ws[i] = Wgn[i];
  __syncthreads();

  // Phase 2: += agg @ Wgn
  for (int k = 0; k < DU; ++k) {
    float a0 = As[rowg * 2 + 0][k];
    float a1 = As[rowg * 2 + 1][k];
    const float* wr = &Ws[k * DU + colg * 6];
#pragma unroll
    for (int j = 0; j < 6; ++j) {
      float w = wr[j];
      acc[0][j] = fmaf(a0, w, acc[0][j]);
      acc[1][j] = fmaf(a1, w, acc[1][j]);
    }
  }

  // Epilogue: gate + combine (agg/X re-read from LDS tiles)
#pragma unroll
  for (int r = 0; r < 2; ++r) {
    int lr = rowg * 2 + r;
    int gr = row0 + lr;
    if (gr < N) {
      float* op = Out + gr * DU + colg * 6;
#pragma unroll
      for (int j = 0; j < 6; ++j) {
        int u = colg * 6 + j;
        float g = acc[r][j] + bgi[u] + bgn[u];
        g = 1.f / (1.f + __expf(-g));
        float av = As[lr][u];
        float xv = Xs[lr][u];
        op[j] = av * g + xv * (1.f - g);
      }
    }
  }
}

extern "C" void kernel_launch(void* const* d_in, const int* in_sizes, int n_in,
                              void* d_out, int out_size, void* d_ws, size_t ws_size,
                              hipStream_t stream) {
  const float* X      = (const float*)d_in[0];
  const float* a_vals = (const float*)d_in[1];
  const float* Wn     = (const float*)d_in[2];
  const float* bn     = (const float*)d_in[3];
  const float* Wgi    = (const float*)d_in[4];
  const float* bgi    = (const float*)d_in[5];
  const float* Wgn    = (const float*)d_in[6];
  const float* bgn    = (const float*)d_in[7];
  const int*   row    = (const int*)d_in[8];
  const int*   col    = (const int*)d_in[9];
  float* out = (float*)d_out;

  const int N = in_sizes[0] / DU;
  const int E = in_sizes[1];

  float* newX = (float*)d_ws;
  float* agg  = newX + (size_t)N * DU;

  hipMemsetAsync(agg, 0, (size_t)N * DU * sizeof(float), stream);

  k_newX<<<(N + 63) / 64, 256, 0, stream>>>(X, Wn, bn, newX, N);
  k_scatter<<<(E * DU4 + 255) / 256, 256, 0, stream>>>(newX, a_vals, row, col, agg, E);
  k_gate<<<(N + 31) / 32, 256, 0, stream>>>(X, agg, Wgi, Wgn, bgi, bgn, out, N);
}

// Round 2
// 416.510 us; speedup vs baseline: 2.8061x; 2.8061x over previous
//
#include <hip/hip_runtime.h>
#include <math.h>

// GatedGCN forward, fp32. D = U = 96 hard-coded.
// newX = X@Wn+bn ; agg = segment_sum(a * newX[col] -> row) via on-device CSR
// gate = sigmoid(X@Wgi + agg@Wgn + bgi + bgn) ; out = agg*gate + X*(1-gate)

#define DU 96
#define DU4 24  // DU/4 float4 chunks per row

// ---------------- Kernel A: newX = X @ Wn + bn ----------------
__global__ __launch_bounds__(256) void k_newX(const float* __restrict__ X,
                                              const float* __restrict__ W,
                                              const float* __restrict__ b,
                                              float* __restrict__ Y, int N) {
  __shared__ float Xs[64][97];
  __shared__ float Ws[DU * DU];
  const int tid = threadIdx.x;
  const int row0 = blockIdx.x * 64;

  for (int i = tid; i < DU * DU; i += 256) Ws[i] = W[i];
  for (int i = tid; i < 64 * DU4; i += 256) {
    int r = i / DU4, c = i % DU4;
    int gr = row0 + r;
    float4 v = make_float4(0.f, 0.f, 0.f, 0.f);
    if (gr < N) v = ((const float4*)X)[gr * DU4 + c];
    Xs[r][4 * c + 0] = v.x;
    Xs[r][4 * c + 1] = v.y;
    Xs[r][4 * c + 2] = v.z;
    Xs[r][4 * c + 3] = v.w;
  }
  __syncthreads();

  const int colg = tid & 15;
  const int rowg = tid >> 4;
  float acc[4][6];
#pragma unroll
  for (int r = 0; r < 4; ++r)
#pragma unroll
    for (int j = 0; j < 6; ++j) acc[r][j] = 0.f;

  for (int k = 0; k < DU; ++k) {
    float x0 = Xs[rowg * 4 + 0][k];
    float x1 = Xs[rowg * 4 + 1][k];
    float x2 = Xs[rowg * 4 + 2][k];
    float x3 = Xs[rowg * 4 + 3][k];
    const float* wr = &Ws[k * DU + colg * 6];
#pragma unroll
    for (int j = 0; j < 6; ++j) {
      float w = wr[j];
      acc[0][j] = fmaf(x0, w, acc[0][j]);
      acc[1][j] = fmaf(x1, w, acc[1][j]);
      acc[2][j] = fmaf(x2, w, acc[2][j]);
      acc[3][j] = fmaf(x3, w, acc[3][j]);
    }
  }

#pragma unroll
  for (int r = 0; r < 4; ++r) {
    int gr = row0 + rowg * 4 + r;
    if (gr < N) {
      float* yp = Y + gr * DU + colg * 6;
#pragma unroll
      for (int j = 0; j < 6; ++j) yp[j] = acc[r][j] + b[colg * 6 + j];
    }
  }
}

// ---------------- CSR build: histogram ----------------
__global__ __launch_bounds__(256) void k_hist(const int* __restrict__ row,
                                              int* __restrict__ hist, int E) {
  int i = blockIdx.x * 256 + threadIdx.x;
  if (i < E) atomicAdd(&hist[row[i]], 1);
}

// ---------------- CSR build: single-block exclusive scan ----------------
__global__ __launch_bounds__(1024) void k_scan(const int* __restrict__ hist,
                                               int* __restrict__ rowptr,
                                               int* __restrict__ cursor, int N) {
  __shared__ int part[1024];
  const int t = threadIdx.x;
  const int chunk = (N + 1023) / 1024;
  const int lo = t * chunk;
  const int hi = min(lo + chunk, N);
  int sum = 0;
  for (int i = lo; i < hi; ++i) sum += hist[i];
  part[t] = sum;
  __syncthreads();
  // Hillis-Steele inclusive scan (read phase / barrier / write phase)
  for (int off = 1; off < 1024; off <<= 1) {
    int v = part[t];
    int add = (t >= off) ? part[t - off] : 0;
    __syncthreads();
    part[t] = v + add;
    __syncthreads();
  }
  int run = (t == 0) ? 0 : part[t - 1];
  for (int i = lo; i < hi; ++i) {
    rowptr[i] = run;
    cursor[i] = run;
    run += hist[i];
  }
  if (t == 1023) rowptr[N] = part[1023];
}

// ---------------- CSR build: fill sorted (col, a) ----------------
__global__ __launch_bounds__(256) void k_fill(const int* __restrict__ row,
                                              const int* __restrict__ col,
                                              const float* __restrict__ a_vals,
                                              int* __restrict__ cursor,
                                              int* __restrict__ scol,
                                              float* __restrict__ sa, int E) {
  int i = blockIdx.x * 256 + threadIdx.x;
  if (i < E) {
    int d = row[i];
    int slot = atomicAdd(&cursor[d], 1);
    scol[slot] = col[i];
    sa[slot] = a_vals[i];
  }
}

// ---------------- Kernel C: CSR-aggregate + gate + combine ----------------
// 32 rows/block, 256 threads. Aggregation: 8 threads/row x 12 dims (3 float4).
__global__ __launch_bounds__(256) void k_gate2(const float* __restrict__ X,
                                               const float* __restrict__ newX,
                                               const int* __restrict__ rowptr,
                                               const int* __restrict__ scol,
                                               const float* __restrict__ sa,
                                               const float* __restrict__ Wgi,
                                               const float* __restrict__ Wgn,
                                               const float* __restrict__ bgi,
                                               const float* __restrict__ bgn,
                                               float* __restrict__ Out, int N) {
  __shared__ float Xs[32][97];
  __shared__ float As[32][97];
  __shared__ float Ws[DU * DU];
  const int tid = threadIdx.x;
  const int row0 = blockIdx.x * 32;

  // Stage X tile
  for (int i = tid; i < 32 * DU4; i += 256) {
    int r = i / DU4, c = i % DU4;
    int gr = row0 + r;
    float4 vx = make_float4(0.f, 0.f, 0.f, 0.f);
    if (gr < N) vx = ((const float4*)X)[gr * DU4 + c];
    Xs[r][4 * c + 0] = vx.x; Xs[r][4 * c + 1] = vx.y;
    Xs[r][4 * c + 2] = vx.z; Xs[r][4 * c + 3] = vx.w;
  }
  // Stage Wgi
  for (int i = tid; i < DU * DU; i += 256) Ws[i] = Wgi[i];

  // CSR aggregation into As: r = tid>>3 (32 rows), sub = tid&7 (12 dims each)
  {
    const int r = tid >> 3;
    const int sub = tid & 7;
    const int gr = row0 + r;
    float4 a0 = make_float4(0.f, 0.f, 0.f, 0.f);
    float4 a1 = a0, a2 = a0;
    if (gr < N) {
      const int e0 = rowptr[gr];
      const int e1 = rowptr[gr + 1];
      for (int e = e0; e < e1; ++e) {
        int cs = scol[e];
        float av = sa[e];
        const float4* src = ((const float4*)newX) + (size_t)cs * DU4 + sub * 3;
        float4 v0 = src[0], v1 = src[1], v2 = src[2];
        a0.x = fmaf(av, v0.x, a0.x); a0.y = fmaf(av, v0.y, a0.y);
        a0.z = fmaf(av, v0.z, a0.z); a0.w = fmaf(av, v0.w, a0.w);
        a1.x = fmaf(av, v1.x, a1.x); a1.y = fmaf(av, v1.y, a1.y);
        a1.z = fmaf(av, v1.z, a1.z); a1.w = fmaf(av, v1.w, a1.w);
        a2.x = fmaf(av, v2.x, a2.x); a2.y = fmaf(av, v2.y, a2.y);
        a2.z = fmaf(av, v2.z, a2.z); a2.w = fmaf(av, v2.w, a2.w);
      }
    }
    float* ap = &As[r][sub * 12];
    ap[0] = a0.x; ap[1] = a0.y; ap[2]  = a0.z; ap[3]  = a0.w;
    ap[4] = a1.x; ap[5] = a1.y; ap[6]  = a1.z; ap[7]  = a1.w;
    ap[8] = a2.x; ap[9] = a2.y; ap[10] = a2.z; ap[11] = a2.w;
  }
  __syncthreads();

  const int colg = tid & 15;   // 16 x 6 cols
  const int rowg = tid >> 4;   // 16 x 2 rows
  float acc[2][6];
#pragma unroll
  for (int r = 0; r < 2; ++r)
#pragma unroll
    for (int j = 0; j < 6; ++j) acc[r][j] = 0.f;

  // Phase 1: X @ Wgi
  for (int k = 0; k < DU; ++k) {
    float x0 = Xs[rowg * 2 + 0][k];
    float x1 = Xs[rowg * 2 + 1][k];
    const float* wr = &Ws[k * DU + colg * 6];
#pragma unroll
    for (int j = 0; j < 6; ++j) {
      float w = wr[j];
      acc[0][j] = fmaf(x0, w, acc[0][j]);
      acc[1][j] = fmaf(x1, w, acc[1][j]);
    }
  }
  __syncthreads();
  for (int i = tid; i < DU * DU; i += 256) Ws[i] = Wgn[i];
  __syncthreads();

  // Phase 2: += agg @ Wgn
  for (int k = 0; k < DU; ++k) {
    float a0 = As[rowg * 2 + 0][k];
    float a1 = As[rowg * 2 + 1][k];
    const float* wr = &Ws[k * DU + colg * 6];
#pragma unroll
    for (int j = 0; j < 6; ++j) {
      float w = wr[j];
      acc[0][j] = fmaf(a0, w, acc[0][j]);
      acc[1][j] = fmaf(a1, w, acc[1][j]);
    }
  }

  // Epilogue: gate + combine
#pragma unroll
  for (int r = 0; r < 2; ++r) {
    int lr = rowg * 2 + r;
    int gr = row0 + lr;
    if (gr < N) {
      float* op = Out + gr * DU + colg * 6;
#pragma unroll
      for (int j = 0; j < 6; ++j) {
        int u = colg * 6 + j;
        float g = acc[r][j] + bgi[u] + bgn[u];
        g = 1.f / (1.f + __expf(-g));
        float av = As[lr][u];
        float xv = Xs[lr][u];
        op[j] = av * g + xv * (1.f - g);
      }
    }
  }
}

extern "C" void kernel_launch(void* const* d_in, const int* in_sizes, int n_in,
                              void* d_out, int out_size, void* d_ws, size_t ws_size,
                              hipStream_t stream) {
  const float* X      = (const float*)d_in[0];
  const float* a_vals = (const float*)d_in[1];
  const float* Wn     = (const float*)d_in[2];
  const float* bn     = (const float*)d_in[3];
  const float* Wgi    = (const float*)d_in[4];
  const float* bgi    = (const float*)d_in[5];
  const float* Wgn    = (const float*)d_in[6];
  const float* bgn    = (const float*)d_in[7];
  const int*   row    = (const int*)d_in[8];
  const int*   col    = (const int*)d_in[9];
  float* out = (float*)d_out;

  const int N = in_sizes[0] / DU;
  const int E = in_sizes[1];

  // Workspace layout (~26 MB)
  float* newX  = (float*)d_ws;                 // N*DU floats
  int*   hist  = (int*)(newX + (size_t)N * DU); // N
  int*   rowptr = hist + N;                    // N+1
  int*   cursor = rowptr + N + 1;              // N
  int*   scol   = cursor + N;                  // E
  float* sa     = (float*)(scol + E);          // E

  hipMemsetAsync(hist, 0, (size_t)N * sizeof(int), stream);

  k_newX<<<(N + 63) / 64, 256, 0, stream>>>(X, Wn, bn, newX, N);
  k_hist<<<(E + 255) / 256, 256, 0, stream>>>(row, hist, E);
  k_scan<<<1, 1024, 0, stream>>>(hist, rowptr, cursor, N);
  k_fill<<<(E + 255) / 256, 256, 0, stream>>>(row, col, a_vals, cursor, scol, sa, E);
  k_gate2<<<(N + 31) / 32, 256, 0, stream>>>(X, newX, rowptr, scol, sa,
                                             Wgi, Wgn, bgi, bgn, out, N);
}

// Round 3
// 303.975 us; speedup vs baseline: 3.8449x; 1.3702x over previous
//
#include <hip/hip_runtime.h>
#include <math.h>

// GatedGCN forward, fp32 in/out. D = U = 96 hard-coded.
// newX = bf16(X@Wn+bn) ; agg = segment_sum(a * newX[col] -> row) via on-device CSR
// gate = sigmoid(X@Wgi + agg@Wgn + bgi + bgn) ; out = agg*gate + X*(1-gate)

#define DU 96
#define DU4 24  // DU/4 float4 chunks per row

typedef unsigned int uint;
typedef unsigned short ushort;

__device__ inline uint bf16r(float x) {  // fp32 -> bf16 bits, round-nearest-even
  uint u = __float_as_uint(x);
  return (u + 0x7FFFu + ((u >> 16) & 1u)) >> 16;
}

// ---------------- Kernel A: newX = bf16(X @ Wn + bn) ----------------
// 64 rows/block, 256 threads, 4x6 register tile per thread.
__global__ __launch_bounds__(256) void k_newX(const float* __restrict__ X,
                                              const float* __restrict__ W,
                                              const float* __restrict__ b,
                                              ushort* __restrict__ Y, int N) {
  __shared__ float Xs[64][97];
  __shared__ float Ws[DU * DU];
  const int tid = threadIdx.x;
  const int row0 = blockIdx.x * 64;

  for (int i = tid; i < DU * DU; i += 256) Ws[i] = W[i];
  for (int i = tid; i < 64 * DU4; i += 256) {
    int r = i / DU4, c = i % DU4;
    int gr = row0 + r;
    float4 v = make_float4(0.f, 0.f, 0.f, 0.f);
    if (gr < N) v = ((const float4*)X)[gr * DU4 + c];
    Xs[r][4 * c + 0] = v.x;
    Xs[r][4 * c + 1] = v.y;
    Xs[r][4 * c + 2] = v.z;
    Xs[r][4 * c + 3] = v.w;
  }
  __syncthreads();

  const int colg = tid & 15;   // 16 groups x 6 cols
  const int rowg = tid >> 4;   // 16 groups x 4 rows
  float acc[4][6];
#pragma unroll
  for (int r = 0; r < 4; ++r)
#pragma unroll
    for (int j = 0; j < 6; ++j) acc[r][j] = 0.f;

  for (int k = 0; k < DU; ++k) {
    float x0 = Xs[rowg * 4 + 0][k];
    float x1 = Xs[rowg * 4 + 1][k];
    float x2 = Xs[rowg * 4 + 2][k];
    float x3 = Xs[rowg * 4 + 3][k];
    const float2* wr2 = (const float2*)&Ws[k * DU + colg * 6];  // colg*24B, 8B aligned
    float2 wa = wr2[0], wb = wr2[1], wc = wr2[2];
    float w[6] = {wa.x, wa.y, wb.x, wb.y, wc.x, wc.y};
#pragma unroll
    for (int j = 0; j < 6; ++j) {
      acc[0][j] = fmaf(x0, w[j], acc[0][j]);
      acc[1][j] = fmaf(x1, w[j], acc[1][j]);
      acc[2][j] = fmaf(x2, w[j], acc[2][j]);
      acc[3][j] = fmaf(x3, w[j], acc[3][j]);
    }
  }

#pragma unroll
  for (int r = 0; r < 4; ++r) {
    int gr = row0 + rowg * 4 + r;
    if (gr < N) {
      uint* yp = (uint*)(Y + gr * DU + colg * 6);  // 4B aligned (colg*12 B)
#pragma unroll
      for (int p = 0; p < 3; ++p) {
        float v0 = acc[r][2 * p + 0] + b[colg * 6 + 2 * p + 0];
        float v1 = acc[r][2 * p + 1] + b[colg * 6 + 2 * p + 1];
        yp[p] = bf16r(v0) | (bf16r(v1) << 16);
      }
    }
  }
}

// ---------------- CSR build: histogram ----------------
__global__ __launch_bounds__(256) void k_hist(const int* __restrict__ row,
                                              int* __restrict__ hist, int E) {
  int i = blockIdx.x * 256 + threadIdx.x;
  if (i < E) atomicAdd(&hist[row[i]], 1);
}

// ---------------- Hierarchical scan: phase 1 (local scan, 1024 elems/block) ----
__global__ __launch_bounds__(256) void k_scan1(const int* __restrict__ hist,
                                               int* __restrict__ cursor,
                                               int* __restrict__ bsum, int N) {
  __shared__ int sm[256];
  const int t = threadIdx.x;
  const int idx = blockIdx.x * 1024 + t * 4;
  int4 h = make_int4(0, 0, 0, 0);
  if (idx < N) h = *(const int4*)(hist + idx);  // N % 4 == 0
  int s = h.x + h.y + h.z + h.w;
  sm[t] = s;
  __syncthreads();
  for (int off = 1; off < 256; off <<= 1) {
    int v = sm[t];
    int add = (t >= off) ? sm[t - off] : 0;
    __syncthreads();
    sm[t] = v + add;
    __syncthreads();
  }
  int excl = sm[t] - s;  // exclusive within block
  if (idx < N) {
    int4 c;
    c.x = excl;
    c.y = excl + h.x;
    c.z = excl + h.x + h.y;
    c.w = excl + h.x + h.y + h.z;
    *(int4*)(cursor + idx) = c;
  }
  if (t == 255) bsum[blockIdx.x] = sm[255];
}

// ---------------- Hierarchical scan: phase 2 (scan of block sums) ----------
__global__ __launch_bounds__(64) void k_scan2(const int* __restrict__ bsum,
                                              int* __restrict__ boff, int NB) {
  __shared__ int sm[64];
  const int t = threadIdx.x;
  int v = (t < NB) ? bsum[t] : 0;
  sm[t] = v;
  __syncthreads();
  for (int off = 1; off < 64; off <<= 1) {
    int x = sm[t];
    int add = (t >= off) ? sm[t - off] : 0;
    __syncthreads();
    sm[t] = x + add;
    __syncthreads();
  }
  if (t < NB) boff[t] = sm[t] - v;  // exclusive
}

// ---------------- Hierarchical scan: phase 3 (add block offsets) ----------
__global__ __launch_bounds__(256) void k_scan3(int* __restrict__ cursor,
                                               const int* __restrict__ boff, int N) {
  const int idx = blockIdx.x * 1024 + threadIdx.x * 4;
  if (idx < N) {
    int o = boff[blockIdx.x];
    int4 c = *(int4*)(cursor + idx);
    c.x += o; c.y += o; c.z += o; c.w += o;
    *(int4*)(cursor + idx) = c;
  }
}

// ---------------- CSR build: fill packed (col, a) sorted by dest ----------
// After this kernel, cursor[r] == end(r) == start(r+1); start(0) == 0.
__global__ __launch_bounds__(256) void k_fill(const int* __restrict__ row,
                                              const int* __restrict__ col,
                                              const float* __restrict__ a_vals,
                                              int* __restrict__ cursor,
                                              int2* __restrict__ epack, int E) {
  int i = blockIdx.x * 256 + threadIdx.x;
  if (i < E) {
    int d = row[i];
    int slot = atomicAdd(&cursor[d], 1);
    epack[slot] = make_int2(col[i], __float_as_int(a_vals[i]));
  }
}

// ---------------- Aggregation: agg[r] = sum_e a_e * newX[col_e] ----------
// One thread per (row, 4-dim chunk): 24 chunk-threads per row. No LDS.
__global__ __launch_bounds__(256) void k_agg(const ushort* __restrict__ newXb,
                                             const int* __restrict__ cursor,
                                             const int2* __restrict__ epack,
                                             float* __restrict__ agg, int N) {
  int i = blockIdx.x * 256 + threadIdx.x;
  int r = i / DU4;
  int c = i % DU4;
  if (r >= N) return;
  int e0 = (r == 0) ? 0 : cursor[r - 1];
  int e1 = cursor[r];
  float4 acc = make_float4(0.f, 0.f, 0.f, 0.f);
  for (int e = e0; e < e1; ++e) {
    int2 p = epack[e];
    float a = __int_as_float(p.y);
    uint2 q = *(const uint2*)(newXb + (size_t)p.x * DU + c * 4);
    float v0 = __uint_as_float(q.x << 16);
    float v1 = __uint_as_float(q.x & 0xFFFF0000u);
    float v2 = __uint_as_float(q.y << 16);
    float v3 = __uint_as_float(q.y & 0xFFFF0000u);
    acc.x = fmaf(a, v0, acc.x);
    acc.y = fmaf(a, v1, acc.y);
    acc.z = fmaf(a, v2, acc.z);
    acc.w = fmaf(a, v3, acc.w);
  }
  ((float4*)agg)[(size_t)r * DU4 + c] = acc;
}

// ---------------- Kernel C: gate + residual combine ----------------
// 32 rows/block, 256 threads, 2x6 tile; two phases share one LDS W buffer.
__global__ __launch_bounds__(256) void k_gate(const float* __restrict__ X,
                                              const float* __restrict__ A,
                                              const float* __restrict__ Wgi,
                                              const float* __restrict__ Wgn,
                                              const float* __restrict__ bgi,
                                              const float* __restrict__ bgn,
                                              float* __restrict__ Out, int N) {
  __shared__ float Xs[32][97];
  __shared__ float As[32][97];
  __shared__ float Ws[DU * DU];
  const int tid = threadIdx.x;
  const int row0 = blockIdx.x * 32;

  for (int i = tid; i < 32 * DU4; i += 256) {
    int r = i / DU4, c = i % DU4;
    int gr = row0 + r;
    float4 vx = make_float4(0.f, 0.f, 0.f, 0.f);
    float4 va = make_float4(0.f, 0.f, 0.f, 0.f);
    if (gr < N) {
      vx = ((const float4*)X)[gr * DU4 + c];
      va = ((const float4*)A)[gr * DU4 + c];
    }
    Xs[r][4 * c + 0] = vx.x; Xs[r][4 * c + 1] = vx.y;
    Xs[r][4 * c + 2] = vx.z; Xs[r][4 * c + 3] = vx.w;
    As[r][4 * c + 0] = va.x; As[r][4 * c + 1] = va.y;
    As[r][4 * c + 2] = va.z; As[r][4 * c + 3] = va.w;
  }
  for (int i = tid; i < DU * DU; i += 256) Ws[i] = Wgi[i];
  __syncthreads();

  const int colg = tid & 15;   // 16 x 6 cols
  const int rowg = tid >> 4;   // 16 x 2 rows
  float acc[2][6];
#pragma unroll
  for (int r = 0; r < 2; ++r)
#pragma unroll
    for (int j = 0; j < 6; ++j) acc[r][j] = 0.f;

  // Phase 1: X @ Wgi
  for (int k = 0; k < DU; ++k) {
    float x0 = Xs[rowg * 2 + 0][k];
    float x1 = Xs[rowg * 2 + 1][k];
    const float2* wr2 = (const float2*)&Ws[k * DU + colg * 6];
    float2 wa = wr2[0], wb = wr2[1], wc = wr2[2];
    float w[6] = {wa.x, wa.y, wb.x, wb.y, wc.x, wc.y};
#pragma unroll
    for (int j = 0; j < 6; ++j) {
      acc[0][j] = fmaf(x0, w[j], acc[0][j]);
      acc[1][j] = fmaf(x1, w[j], acc[1][j]);
    }
  }
  __syncthreads();
  for (int i = tid; i < DU * DU; i += 256) Ws[i] = Wgn[i];
  __syncthreads();

  // Phase 2: += agg @ Wgn
  for (int k = 0; k < DU; ++k) {
    float a0 = As[rowg * 2 + 0][k];
    float a1 = As[rowg * 2 + 1][k];
    const float2* wr2 = (const float2*)&Ws[k * DU + colg * 6];
    float2 wa = wr2[0], wb = wr2[1], wc = wr2[2];
    float w[6] = {wa.x, wa.y, wb.x, wb.y, wc.x, wc.y};
#pragma unroll
    for (int j = 0; j < 6; ++j) {
      acc[0][j] = fmaf(a0, w[j], acc[0][j]);
      acc[1][j] = fmaf(a1, w[j], acc[1][j]);
    }
  }

  // Epilogue: gate + combine
#pragma unroll
  for (int r = 0; r < 2; ++r) {
    int lr = rowg * 2 + r;
    int gr = row0 + lr;
    if (gr < N) {
      float* op = Out + gr * DU + colg * 6;
#pragma unroll
      for (int j = 0; j < 6; ++j) {
        int u = colg * 6 + j;
        float g = acc[r][j] + bgi[u] + bgn[u];
        g = 1.f / (1.f + __expf(-g));
        float av = As[lr][u];
        float xv = Xs[lr][u];
        op[j] = av * g + xv * (1.f - g);
      }
    }
  }
}

extern "C" void kernel_launch(void* const* d_in, const int* in_sizes, int n_in,
                              void* d_out, int out_size, void* d_ws, size_t ws_size,
                              hipStream_t stream) {
  const float* X      = (const float*)d_in[0];
  const float* a_vals = (const float*)d_in[1];
  const float* Wn     = (const float*)d_in[2];
  const float* bn     = (const float*)d_in[3];
  const float* Wgi    = (const float*)d_in[4];
  const float* bgi    = (const float*)d_in[5];
  const float* Wgn    = (const float*)d_in[6];
  const float* bgn    = (const float*)d_in[7];
  const int*   row    = (const int*)d_in[8];
  const int*   col    = (const int*)d_in[9];
  float* out = (float*)d_out;

  const int N = in_sizes[0] / DU;
  const int E = in_sizes[1];
  const int NB = (N + 1023) / 1024;  // scan blocks (49 for N=50000)

  // Workspace layout (~35.9 MB total, fp32 agg first for 16B alignment)
  float*  agg    = (float*)d_ws;                      // N*DU floats   (19.2 MB)
  ushort* newXb  = (ushort*)(agg + (size_t)N * DU);   // N*DU ushorts  ( 9.6 MB)
  int2*   epack  = (int2*)(newXb + (size_t)N * DU);   // E int2        ( 6.4 MB)
  int*    hist   = (int*)(epack + E);                 // N
  int*    cursor = hist + N;                          // N
  int*    bsum   = cursor + N;                        // 64
  int*    boff   = bsum + 64;                         // 64

  hipMemsetAsync(hist, 0, (size_t)N * sizeof(int), stream);

  k_newX <<<(N + 63) / 64, 256, 0, stream>>>(X, Wn, bn, newXb, N);
  k_hist <<<(E + 255) / 256, 256, 0, stream>>>(row, hist, E);
  k_scan1<<<NB, 256, 0, stream>>>(hist, cursor, bsum, N);
  k_scan2<<<1, 64, 0, stream>>>(bsum, boff, NB);
  k_scan3<<<NB, 256, 0, stream>>>(cursor, boff, N);
  k_fill <<<(E + 255) / 256, 256, 0, stream>>>(row, col, a_vals, cursor, epack, E);
  k_agg  <<<((size_t)N * DU4 + 255) / 256, 256, 0, stream>>>(newXb, cursor, epack, agg, N);
  k_gate <<<(N + 31) / 32, 256, 0, stream>>>(X, agg, Wgi, Wgn, bgi, bgn, out, N);
}

// Round 4
// 235.312 us; speedup vs baseline: 4.9668x; 1.2918x over previous
//
#include <hip/hip_runtime.h>
#include <math.h>

// GatedGCN forward, fp32 in/out. D = U = 96 hard-coded. MFMA bf16 GEMMs.
// newX = bf16(X@Wn+bn) ; agg = bf16(segment_sum(a * newX[col] -> row)) via CSR
// gate = sigmoid(Xb@Wgi + aggb@Wgn + bgi + bgn) ; out = X + gate*(agg - X)

#define DU 96
#define DU4 24  // DU/4 float4 chunks per row

typedef unsigned int uint;
typedef unsigned short ushort;
typedef __attribute__((ext_vector_type(8))) short short8;
typedef __attribute__((ext_vector_type(4))) float f32x4;

__device__ inline uint bf16r(float x) {  // fp32 -> bf16 bits, round-nearest-even
  uint u = __float_as_uint(x);
  return (u + 0x7FFFu + ((u >> 16) & 1u)) >> 16;
}

// ---------- k_prep: Xb = bf16(X); WT* = bf16(W^T); hist of row ----------
__global__ __launch_bounds__(256) void k_prep(const float* __restrict__ X,
                                              const float* __restrict__ Wn,
                                              const float* __restrict__ Wgi,
                                              const float* __restrict__ Wgn,
                                              const int* __restrict__ row,
                                              ushort* __restrict__ Xb,
                                              ushort* __restrict__ WTn,
                                              ushort* __restrict__ WTgi,
                                              ushort* __restrict__ WTgn,
                                              int* __restrict__ hist, int N, int E) {
  const int tid = blockIdx.x * 256 + threadIdx.x;
  const int nth = gridDim.x * 256;
  // transpose-convert weights: WT[n*96+k] = bf16(W[k*96+n])
  for (int i = tid; i < DU * DU; i += nth) {
    int n = i / DU, k = i % DU;
    WTn[i]  = (ushort)bf16r(Wn[k * DU + n]);
    WTgi[i] = (ushort)bf16r(Wgi[k * DU + n]);
    WTgn[i] = (ushort)bf16r(Wgn[k * DU + n]);
  }
  // Xb: pack pairs
  uint* xb = (uint*)Xb;
  const float2* x2 = (const float2*)X;
  const int nx = N * (DU / 2);
  for (int i = tid; i < nx; i += nth) {
    float2 v = x2[i];
    xb[i] = bf16r(v.x) | (bf16r(v.y) << 16);
  }
  // histogram
  for (int i = tid; i < E; i += nth) atomicAdd(&hist[row[i]], 1);
}

// ---------------- Hierarchical scan: phase 1 ----------------
__global__ __launch_bounds__(256) void k_scan1(const int* __restrict__ hist,
                                               int* __restrict__ cursor,
                                               int* __restrict__ bsum, int N) {
  __shared__ int sm[256];
  const int t = threadIdx.x;
  const int idx = blockIdx.x * 1024 + t * 4;
  int4 h = make_int4(0, 0, 0, 0);
  if (idx < N) h = *(const int4*)(hist + idx);  // N % 4 == 0
  int s = h.x + h.y + h.z + h.w;
  sm[t] = s;
  __syncthreads();
  for (int off = 1; off < 256; off <<= 1) {
    int v = sm[t];
    int add = (t >= off) ? sm[t - off] : 0;
    __syncthreads();
    sm[t] = v + add;
    __syncthreads();
  }
  int excl = sm[t] - s;
  if (idx < N) {
    int4 c;
    c.x = excl;
    c.y = excl + h.x;
    c.z = excl + h.x + h.y;
    c.w = excl + h.x + h.y + h.z;
    *(int4*)(cursor + idx) = c;
  }
  if (t == 255) bsum[blockIdx.x] = sm[255];
}

// ---------------- Hierarchical scan: phase 2 ----------------
__global__ __launch_bounds__(64) void k_scan2(const int* __restrict__ bsum,
                                              int* __restrict__ boff, int NB) {
  __shared__ int sm[64];
  const int t = threadIdx.x;
  int v = (t < NB) ? bsum[t] : 0;
  sm[t] = v;
  __syncthreads();
  for (int off = 1; off < 64; off <<= 1) {
    int x = sm[t];
    int add = (t >= off) ? sm[t - off] : 0;
    __syncthreads();
    sm[t] = x + add;
    __syncthreads();
  }
  if (t < NB) boff[t] = sm[t] - v;
}

// ---------------- Hierarchical scan: phase 3 ----------------
__global__ __launch_bounds__(256) void k_scan3(int* __restrict__ cursor,
                                               const int* __restrict__ boff, int N) {
  const int idx = blockIdx.x * 1024 + threadIdx.x * 4;
  if (idx < N) {
    int o = boff[blockIdx.x];
    int4 c = *(int4*)(cursor + idx);
    c.x += o; c.y += o; c.z += o; c.w += o;
    *(int4*)(cursor + idx) = c;
  }
}

// ---------------- CSR fill: packed (col, a) sorted by dest ----------------
__global__ __launch_bounds__(256) void k_fill(const int* __restrict__ row,
                                              const int* __restrict__ col,
                                              const float* __restrict__ a_vals,
                                              int* __restrict__ cursor,
                                              int2* __restrict__ epack, int E) {
  int i = blockIdx.x * 256 + threadIdx.x;
  if (i < E) {
    int d = row[i];
    int slot = atomicAdd(&cursor[d], 1);
    epack[slot] = make_int2(col[i], __float_as_int(a_vals[i]));
  }
}

// ---------- k_newXM: newXb = bf16(Xb @ Wn + bn), MFMA 16x16x32 ----------
// 64 rows/block (4 waves x 16 rows), 6 col-tiles, K = 3 steps of 32.
__global__ __launch_bounds__(256) void k_newXM(const ushort* __restrict__ Xb,
                                               const ushort* __restrict__ WT,
                                               const float* __restrict__ bias,
                                               ushort* __restrict__ Y, int N) {
  __shared__ ushort Ys[64][104];
  const int tid = threadIdx.x;
  const int lane = tid & 63, w = tid >> 6;
  const int m = lane & 15, q = lane >> 4;
  const int row0 = blockIdx.x * 64;
  int ar = row0 + w * 16 + m;
  if (ar > N - 1) ar = N - 1;

  f32x4 zero = {0.f, 0.f, 0.f, 0.f};
  f32x4 acc[6];
#pragma unroll
  for (int t = 0; t < 6; ++t) acc[t] = zero;

#pragma unroll
  for (int ks = 0; ks < 3; ++ks) {
    short8 af = *(const short8*)(Xb + (size_t)ar * DU + ks * 32 + q * 8);
#pragma unroll
    for (int t = 0; t < 6; ++t) {
      short8 bf = *(const short8*)(WT + (size_t)(t * 16 + m) * DU + ks * 32 + q * 8);
      acc[t] = __builtin_amdgcn_mfma_f32_16x16x32_bf16(af, bf, acc[t], 0, 0, 0);
    }
  }

#pragma unroll
  for (int t = 0; t < 6; ++t) {
    int c = t * 16 + m;
    float bb = bias[c];
#pragma unroll
    for (int i = 0; i < 4; ++i)
      Ys[w * 16 + q * 4 + i][c] = (ushort)bf16r(acc[t][i] + bb);
  }
  __syncthreads();

  uint* yg = (uint*)Y;
  for (int j = tid; j < 64 * 48; j += 256) {
    int r = j / 48, cu = j % 48;
    int gr = row0 + r;
    if (gr < N) yg[(size_t)gr * 48 + cu] = *(uint*)&Ys[r][cu * 2];
  }
}

// ---------- k_agg: aggb[r] = bf16(sum_e a_e * newXb[col_e]) ----------
// One thread per (row, 4-dim chunk); epack software-pipelined.
__global__ __launch_bounds__(256) void k_agg(const ushort* __restrict__ newXb,
                                             const int* __restrict__ cursor,
                                             const int2* __restrict__ epack,
                                             ushort* __restrict__ aggb, int N) {
  int i = blockIdx.x * 256 + threadIdx.x;
  int r = i / DU4;
  int c = i % DU4;
  if (r >= N) return;
  int e0 = (r == 0) ? 0 : cursor[r - 1];
  int e1 = cursor[r];
  float4 acc = make_float4(0.f, 0.f, 0.f, 0.f);
  if (e0 < e1) {
    int2 p = epack[e0];
    for (int e = e0; e < e1; ++e) {
      int2 np = p;
      if (e + 1 < e1) np = epack[e + 1];
      float a = __int_as_float(p.y);
      uint2 v = *(const uint2*)(newXb + (size_t)p.x * DU + c * 4);
      acc.x = fmaf(a, __uint_as_float(v.x << 16), acc.x);
      acc.y = fmaf(a, __uint_as_float(v.x & 0xFFFF0000u), acc.y);
      acc.z = fmaf(a, __uint_as_float(v.y << 16), acc.z);
      acc.w = fmaf(a, __uint_as_float(v.y & 0xFFFF0000u), acc.w);
      p = np;
    }
  }
  uint2 o;
  o.x = bf16r(acc.x) | (bf16r(acc.y) << 16);
  o.y = bf16r(acc.z) | (bf16r(acc.w) << 16);
  ((uint2*)aggb)[(size_t)r * DU4 + c] = o;
}

// ---------- k_gateM: z = Xb@Wgi + aggb@Wgn + b; out = X + g*(agg-X) ----------
__global__ __launch_bounds__(256) void k_gateM(const ushort* __restrict__ Xb,
                                               const ushort* __restrict__ aggb,
                                               const ushort* __restrict__ WTgi,
                                               const ushort* __restrict__ WTgn,
                                               const float* __restrict__ bgi,
                                               const float* __restrict__ bgn,
                                               const float* __restrict__ X,
                                               float* __restrict__ Out, int N) {
  __shared__ float Gs[64][100];
  const int tid = threadIdx.x;
  const int lane = tid & 63, w = tid >> 6;
  const int m = lane & 15, q = lane >> 4;
  const int row0 = blockIdx.x * 64;
  int ar = row0 + w * 16 + m;
  if (ar > N - 1) ar = N - 1;

  f32x4 zero = {0.f, 0.f, 0.f, 0.f};
  f32x4 acc[6];
#pragma unroll
  for (int t = 0; t < 6; ++t) acc[t] = zero;

  // Phase 1: Xb @ Wgi
#pragma unroll
  for (int ks = 0; ks < 3; ++ks) {
    short8 af = *(const short8*)(Xb + (size_t)ar * DU + ks * 32 + q * 8);
#pragma unroll
    for (int t = 0; t < 6; ++t) {
      short8 bf = *(const short8*)(WTgi + (size_t)(t * 16 + m) * DU + ks * 32 + q * 8);
      acc[t] = __builtin_amdgcn_mfma_f32_16x16x32_bf16(af, bf, acc[t], 0, 0, 0);
    }
  }
  // Phase 2: += aggb @ Wgn
#pragma unroll
  for (int ks = 0; ks < 3; ++ks) {
    short8 af = *(const short8*)(aggb + (size_t)ar * DU + ks * 32 + q * 8);
#pragma unroll
    for (int t = 0; t < 6; ++t) {
      short8 bf = *(const short8*)(WTgn + (size_t)(t * 16 + m) * DU + ks * 32 + q * 8);
      acc[t] = __builtin_amdgcn_mfma_f32_16x16x32_bf16(af, bf, acc[t], 0, 0, 0);
    }
  }

#pragma unroll
  for (int t = 0; t < 6; ++t) {
    int c = t * 16 + m;
    float bb = bgi[c] + bgn[c];
#pragma unroll
    for (int i = 0; i < 4; ++i) {
      float z = acc[t][i] + bb;
      Gs[w * 16 + q * 4 + i][c] = 1.f / (1.f + __expf(-z));
    }
  }
  __syncthreads();

  // Epilogue: linear, coalesced. out = x + g*(a - x)
  for (int j = tid; j < 64 * DU4; j += 256) {
    int r = j / DU4, c = j % DU4;
    int gr = row0 + r;
    if (gr < N) {
      float4 xv = ((const float4*)X)[(size_t)gr * DU4 + c];
      uint2 av = ((const uint2*)aggb)[(size_t)gr * DU4 + c];
      float a0 = __uint_as_float(av.x << 16);
      float a1 = __uint_as_float(av.x & 0xFFFF0000u);
      float a2 = __uint_as_float(av.y << 16);
      float a3 = __uint_as_float(av.y & 0xFFFF0000u);
      const float* gp = &Gs[r][c * 4];
      float4 o;
      o.x = xv.x + gp[0] * (a0 - xv.x);
      o.y = xv.y + gp[1] * (a1 - xv.y);
      o.z = xv.z + gp[2] * (a2 - xv.z);
      o.w = xv.w + gp[3] * (a3 - xv.w);
      ((float4*)Out)[(size_t)gr * DU4 + c] = o;
    }
  }
}

extern "C" void kernel_launch(void* const* d_in, const int* in_sizes, int n_in,
                              void* d_out, int out_size, void* d_ws, size_t ws_size,
                              hipStream_t stream) {
  const float* X      = (const float*)d_in[0];
  const float* a_vals = (const float*)d_in[1];
  const float* Wn     = (const float*)d_in[2];
  const float* bn     = (const float*)d_in[3];
  const float* Wgi    = (const float*)d_in[4];
  const float* bgi    = (const float*)d_in[5];
  const float* Wgn    = (const float*)d_in[6];
  const float* bgn    = (const float*)d_in[7];
  const int*   row    = (const int*)d_in[8];
  const int*   col    = (const int*)d_in[9];
  float* out = (float*)d_out;

  const int N = in_sizes[0] / DU;
  const int E = in_sizes[1];
  const int NB = (N + 1023) / 1024;  // 49 for N=50000

  // Workspace (~35.7 MB): all offsets 16B-aligned
  ushort* Xb    = (ushort*)d_ws;                  // N*96 bf16  (9.6 MB)
  ushort* newXb = Xb + (size_t)N * DU;            // 9.6 MB
  ushort* aggb  = newXb + (size_t)N * DU;         // 9.6 MB
  ushort* WTn   = aggb + (size_t)N * DU;          // 18 KB
  ushort* WTgi  = WTn + DU * DU;
  ushort* WTgn  = WTgi + DU * DU;
  int2*   epack = (int2*)(WTgn + DU * DU);        // 6.4 MB
  int*    hist   = (int*)(epack + E);             // N
  int*    cursor = hist + N;                      // N
  int*    bsum   = cursor + N;                    // 64
  int*    boff   = bsum + 64;                     // 64

  hipMemsetAsync(hist, 0, (size_t)N * sizeof(int), stream);

  k_prep <<<1024, 256, 0, stream>>>(X, Wn, Wgi, Wgn, row, Xb, WTn, WTgi, WTgn, hist, N, E);
  k_scan1<<<NB, 256, 0, stream>>>(hist, cursor, bsum, N);
  k_scan2<<<1, 64, 0, stream>>>(bsum, boff, NB);
  k_scan3<<<NB, 256, 0, stream>>>(cursor, boff, N);
  k_fill <<<(E + 255) / 256, 256, 0, stream>>>(row, col, a_vals, cursor, epack, E);
  k_newXM<<<(N + 63) / 64, 256, 0, stream>>>(Xb, WTn, bn, newXb, N);
  k_agg  <<<((size_t)N * DU4 + 255) / 256, 256, 0, stream>>>(newXb, cursor, epack, aggb, N);
  k_gateM<<<(N + 63) / 64, 256, 0, stream>>>(Xb, aggb, WTgi, WTgn, bgi, bgn, X, out, N);
}

// Round 5
// 222.993 us; speedup vs baseline: 5.2412x; 1.0552x over previous
//
#include <hip/hip_runtime.h>
#include <math.h>

// GatedGCN forward, fp32 in/out. D = U = 96 hard-coded. MFMA bf16 GEMMs.
// newX = bf16(X@Wn+bn) ; agg = bf16(segment_sum(a * newX[col] -> row)) via CSR
// gate = sigmoid(Xb@Wgi + aggb@Wgn + bgi + bgn) ; out = X + gate*(agg - X)

#define DU 96
#define DU4 24  // DU/4 float4 chunks per row

typedef unsigned int uint;
typedef unsigned short ushort;
typedef __attribute__((ext_vector_type(8))) short short8;
typedef __attribute__((ext_vector_type(4))) float f32x4;

__device__ inline uint bf16r(float x) {  // fp32 -> bf16 bits, round-nearest-even
  uint u = __float_as_uint(x);
  return (u + 0x7FFFu + ((u >> 16) & 1u)) >> 16;
}

// ---------- k_prep: Xb = bf16(X); WT* = bf16(W^T); hist of row ----------
__global__ __launch_bounds__(256) void k_prep(const float* __restrict__ X,
                                              const float* __restrict__ Wn,
                                              const float* __restrict__ Wgi,
                                              const float* __restrict__ Wgn,
                                              const int* __restrict__ row,
                                              ushort* __restrict__ Xb,
                                              ushort* __restrict__ WTn,
                                              ushort* __restrict__ WTgi,
                                              ushort* __restrict__ WTgn,
                                              int* __restrict__ hist, int N, int E) {
  const int tid = blockIdx.x * 256 + threadIdx.x;
  const int nth = gridDim.x * 256;
  // transpose-convert weights: WT[n*96+k] = bf16(W[k*96+n])
  for (int i = tid; i < DU * DU; i += nth) {
    int n = i / DU, k = i % DU;
    WTn[i]  = (ushort)bf16r(Wn[k * DU + n]);
    WTgi[i] = (ushort)bf16r(Wgi[k * DU + n]);
    WTgn[i] = (ushort)bf16r(Wgn[k * DU + n]);
  }
  // Xb: pack pairs
  uint* xb = (uint*)Xb;
  const float2* x2 = (const float2*)X;
  const int nx = N * (DU / 2);
  for (int i = tid; i < nx; i += nth) {
    float2 v = x2[i];
    xb[i] = bf16r(v.x) | (bf16r(v.y) << 16);
  }
  // histogram
  for (int i = tid; i < E; i += nth) atomicAdd(&hist[row[i]], 1);
}

// ---------------- Hierarchical scan: phase 1 (local scan, 1024/block) ------
__global__ __launch_bounds__(256) void k_scan1(const int* __restrict__ hist,
                                               int* __restrict__ cursor,
                                               int* __restrict__ bsum, int N) {
  __shared__ int sm[256];
  const int t = threadIdx.x;
  const int idx = blockIdx.x * 1024 + t * 4;
  int4 h = make_int4(0, 0, 0, 0);
  if (idx < N) h = *(const int4*)(hist + idx);  // N % 4 == 0
  int s = h.x + h.y + h.z + h.w;
  sm[t] = s;
  __syncthreads();
  for (int off = 1; off < 256; off <<= 1) {
    int v = sm[t];
    int add = (t >= off) ? sm[t - off] : 0;
    __syncthreads();
    sm[t] = v + add;
    __syncthreads();
  }
  int excl = sm[t] - s;
  if (idx < N) {
    int4 c;
    c.x = excl;
    c.y = excl + h.x;
    c.z = excl + h.x + h.y;
    c.w = excl + h.x + h.y + h.z;
    *(int4*)(cursor + idx) = c;
  }
  if (t == 255) bsum[blockIdx.x] = sm[255];
}

// ---- scan phase 2+3 fused: block offset via in-kernel wave prefix of bsum ----
__global__ __launch_bounds__(256) void k_scan3(int* __restrict__ cursor,
                                               const int* __restrict__ bsum, int N) {
  __shared__ int s_off;
  if (threadIdx.x < 64) {
    int v = (threadIdx.x < blockIdx.x) ? bsum[threadIdx.x] : 0;  // NB <= 64
    for (int off = 32; off > 0; off >>= 1) v += __shfl_down(v, off);
    if (threadIdx.x == 0) s_off = v;
  }
  __syncthreads();
  const int idx = blockIdx.x * 1024 + threadIdx.x * 4;
  if (idx < N) {
    int o = s_off;
    int4 c = *(int4*)(cursor + idx);
    c.x += o; c.y += o; c.z += o; c.w += o;
    *(int4*)(cursor + idx) = c;
  }
}

// ---------------- CSR fill: XCD-partitioned by destination range ----------
// 8 groups (g = blockIdx & 7 -> same XCD under round-robin dispatch); group g
// scans ALL edges but handles only dests in its 1/8 range, so every epack
// cache line is written by exactly one XCD's L2 (kills the 8x write-back
// amplification seen in R4: WRITE_SIZE 52 MB for 6.4 MB payload).
// Correctness does NOT depend on the XCD mapping (unique slots via atomics).
__global__ __launch_bounds__(256) void k_fill(const int* __restrict__ row,
                                              const int* __restrict__ col,
                                              const float* __restrict__ a_vals,
                                              int* __restrict__ cursor,
                                              int2* __restrict__ epack, int E, int N) {
  const int g = blockIdx.x & 7;
  const int sub = blockIdx.x >> 3;
  const int nsub = gridDim.x >> 3;
  const int d0 = (int)((long long)N * g >> 3);
  const int d1 = (int)((long long)N * (g + 1) >> 3);
  for (int i = sub * 256 + threadIdx.x; i < E; i += nsub * 256) {
    int d = row[i];
    if (d >= d0 && d < d1) {
      int slot = atomicAdd(&cursor[d], 1);
      epack[slot] = make_int2(col[i], __float_as_int(a_vals[i]));
    }
  }
}

// ---------- k_newXM: newXb = bf16(Xb @ Wn + bn), MFMA 16x16x32 ----------
__global__ __launch_bounds__(256) void k_newXM(const ushort* __restrict__ Xb,
                                               const ushort* __restrict__ WT,
                                               const float* __restrict__ bias,
                                               ushort* __restrict__ Y, int N) {
  __shared__ ushort Ys[64][104];
  const int tid = threadIdx.x;
  const int lane = tid & 63, w = tid >> 6;
  const int m = lane & 15, q = lane >> 4;
  const int row0 = blockIdx.x * 64;
  int ar = row0 + w * 16 + m;
  if (ar > N - 1) ar = N - 1;

  f32x4 zero = {0.f, 0.f, 0.f, 0.f};
  f32x4 acc[6];
#pragma unroll
  for (int t = 0; t < 6; ++t) acc[t] = zero;

#pragma unroll
  for (int ks = 0; ks < 3; ++ks) {
    short8 af = *(const short8*)(Xb + (size_t)ar * DU + ks * 32 + q * 8);
#pragma unroll
    for (int t = 0; t < 6; ++t) {
      short8 bf = *(const short8*)(WT + (size_t)(t * 16 + m) * DU + ks * 32 + q * 8);
      acc[t] = __builtin_amdgcn_mfma_f32_16x16x32_bf16(af, bf, acc[t], 0, 0, 0);
    }
  }

#pragma unroll
  for (int t = 0; t < 6; ++t) {
    int c = t * 16 + m;
    float bb = bias[c];
#pragma unroll
    for (int i = 0; i < 4; ++i)
      Ys[w * 16 + q * 4 + i][c] = (ushort)bf16r(acc[t][i] + bb);
  }
  __syncthreads();

  uint* yg = (uint*)Y;
  for (int j = tid; j < 64 * 48; j += 256) {
    int r = j / 48, cu = j % 48;
    int gr = row0 + r;
    if (gr < N) yg[(size_t)gr * 48 + cu] = *(uint*)&Ys[r][cu * 2];
  }
}

// ---------- k_agg: aggb[r] = bf16(sum_e a_e * newXb[col_e]) ----------
// One thread per (row, 4-dim chunk); unroll-4 => 4 independent gathers in
// flight per thread (R4 had 1 -> latency-exposed).
__global__ __launch_bounds__(256) void k_agg(const ushort* __restrict__ newXb,
                                             const int* __restrict__ cursor,
                                             const int2* __restrict__ epack,
                                             ushort* __restrict__ aggb, int N) {
  int i = blockIdx.x * 256 + threadIdx.x;
  int r = i / DU4;
  int c = i % DU4;
  if (r >= N) return;
  int e0 = (r == 0) ? 0 : cursor[r - 1];
  int e1 = cursor[r];
  float4 accA = make_float4(0.f, 0.f, 0.f, 0.f);
  float4 accB = make_float4(0.f, 0.f, 0.f, 0.f);
  int e = e0;
  for (; e + 4 <= e1; e += 4) {
    int2 p0 = epack[e + 0];
    int2 p1 = epack[e + 1];
    int2 p2 = epack[e + 2];
    int2 p3 = epack[e + 3];
    uint2 v0 = *(const uint2*)(newXb + (size_t)p0.x * DU + c * 4);
    uint2 v1 = *(const uint2*)(newXb + (size_t)p1.x * DU + c * 4);
    uint2 v2 = *(const uint2*)(newXb + (size_t)p2.x * DU + c * 4);
    uint2 v3 = *(const uint2*)(newXb + (size_t)p3.x * DU + c * 4);
    float a0 = __int_as_float(p0.y), a1 = __int_as_float(p1.y);
    float a2 = __int_as_float(p2.y), a3 = __int_as_float(p3.y);
    accA.x = fmaf(a0, __uint_as_float(v0.x << 16), accA.x);
    accA.y = fmaf(a0, __uint_as_float(v0.x & 0xFFFF0000u), accA.y);
    accA.z = fmaf(a0, __uint_as_float(v0.y << 16), accA.z);
    accA.w = fmaf(a0, __uint_as_float(v0.y & 0xFFFF0000u), accA.w);
    accB.x = fmaf(a1, __uint_as_float(v1.x << 16), accB.x);
    accB.y = fmaf(a1, __uint_as_float(v1.x & 0xFFFF0000u), accB.y);
    accB.z = fmaf(a1, __uint_as_float(v1.y << 16), accB.z);
    accB.w = fmaf(a1, __uint_as_float(v1.y & 0xFFFF0000u), accB.w);
    accA.x = fmaf(a2, __uint_as_float(v2.x << 16), accA.x);
    accA.y = fmaf(a2, __uint_as_float(v2.x & 0xFFFF0000u), accA.y);
    accA.z = fmaf(a2, __uint_as_float(v2.y << 16), accA.z);
    accA.w = fmaf(a2, __uint_as_float(v2.y & 0xFFFF0000u), accA.w);
    accB.x = fmaf(a3, __uint_as_float(v3.x << 16), accB.x);
    accB.y = fmaf(a3, __uint_as_float(v3.x & 0xFFFF0000u), accB.y);
    accB.z = fmaf(a3, __uint_as_float(v3.y << 16), accB.z);
    accB.w = fmaf(a3, __uint_as_float(v3.y & 0xFFFF0000u), accB.w);
  }
  for (; e < e1; ++e) {
    int2 p = epack[e];
    float a = __int_as_float(p.y);
    uint2 v = *(const uint2*)(newXb + (size_t)p.x * DU + c * 4);
    accA.x = fmaf(a, __uint_as_float(v.x << 16), accA.x);
    accA.y = fmaf(a, __uint_as_float(v.x & 0xFFFF0000u), accA.y);
    accA.z = fmaf(a, __uint_as_float(v.y << 16), accA.z);
    accA.w = fmaf(a, __uint_as_float(v.y & 0xFFFF0000u), accA.w);
  }
  accA.x += accB.x; accA.y += accB.y; accA.z += accB.z; accA.w += accB.w;
  uint2 o;
  o.x = bf16r(accA.x) | (bf16r(accA.y) << 16);
  o.y = bf16r(accA.z) | (bf16r(accA.w) << 16);
  ((uint2*)aggb)[(size_t)r * DU4 + c] = o;
}

// ---------- k_gateM: z = Xb@Wgi + aggb@Wgn + b; out = X + g*(agg-X) ----------
__global__ __launch_bounds__(256) void k_gateM(const ushort* __restrict__ Xb,
                                               const ushort* __restrict__ aggb,
                                               const ushort* __restrict__ WTgi,
                                               const ushort* __restrict__ WTgn,
                                               const float* __restrict__ bgi,
                                               const float* __restrict__ bgn,
                                               const float* __restrict__ X,
                                               float* __restrict__ Out, int N) {
  __shared__ float Gs[64][100];
  const int tid = threadIdx.x;
  const int lane = tid & 63, w = tid >> 6;
  const int m = lane & 15, q = lane >> 4;
  const int row0 = blockIdx.x * 64;
  int ar = row0 + w * 16 + m;
  if (ar > N - 1) ar = N - 1;

  f32x4 zero = {0.f, 0.f, 0.f, 0.f};
  f32x4 acc[6];
#pragma unroll
  for (int t = 0; t < 6; ++t) acc[t] = zero;

  // Phase 1: Xb @ Wgi
#pragma unroll
  for (int ks = 0; ks < 3; ++ks) {
    short8 af = *(const short8*)(Xb + (size_t)ar * DU + ks * 32 + q * 8);
#pragma unroll
    for (int t = 0; t < 6; ++t) {
      short8 bf = *(const short8*)(WTgi + (size_t)(t * 16 + m) * DU + ks * 32 + q * 8);
      acc[t] = __builtin_amdgcn_mfma_f32_16x16x32_bf16(af, bf, acc[t], 0, 0, 0);
    }
  }
  // Phase 2: += aggb @ Wgn
#pragma unroll
  for (int ks = 0; ks < 3; ++ks) {
    short8 af = *(const short8*)(aggb + (size_t)ar * DU + ks * 32 + q * 8);
#pragma unroll
    for (int t = 0; t < 6; ++t) {
      short8 bf = *(const short8*)(WTgn + (size_t)(t * 16 + m) * DU + ks * 32 + q * 8);
      acc[t] = __builtin_amdgcn_mfma_f32_16x16x32_bf16(af, bf, acc[t], 0, 0, 0);
    }
  }

#pragma unroll
  for (int t = 0; t < 6; ++t) {
    int c = t * 16 + m;
    float bb = bgi[c] + bgn[c];
#pragma unroll
    for (int i = 0; i < 4; ++i) {
      float z = acc[t][i] + bb;
      Gs[w * 16 + q * 4 + i][c] = 1.f / (1.f + __expf(-z));
    }
  }
  __syncthreads();

  // Epilogue: linear, coalesced. out = x + g*(a - x)
  for (int j = tid; j < 64 * DU4; j += 256) {
    int r = j / DU4, c = j % DU4;
    int gr = row0 + r;
    if (gr < N) {
      float4 xv = ((const float4*)X)[(size_t)gr * DU4 + c];
      uint2 av = ((const uint2*)aggb)[(size_t)gr * DU4 + c];
      float a0 = __uint_as_float(av.x << 16);
      float a1 = __uint_as_float(av.x & 0xFFFF0000u);
      float a2 = __uint_as_float(av.y << 16);
      float a3 = __uint_as_float(av.y & 0xFFFF0000u);
      const float* gp = &Gs[r][c * 4];
      float4 o;
      o.x = xv.x + gp[0] * (a0 - xv.x);
      o.y = xv.y + gp[1] * (a1 - xv.y);
      o.z = xv.z + gp[2] * (a2 - xv.z);
      o.w = xv.w + gp[3] * (a3 - xv.w);
      ((float4*)Out)[(size_t)gr * DU4 + c] = o;
    }
  }
}

extern "C" void kernel_launch(void* const* d_in, const int* in_sizes, int n_in,
                              void* d_out, int out_size, void* d_ws, size_t ws_size,
                              hipStream_t stream) {
  const float* X      = (const float*)d_in[0];
  const float* a_vals = (const float*)d_in[1];
  const float* Wn     = (const float*)d_in[2];
  const float* bn     = (const float*)d_in[3];
  const float* Wgi    = (const float*)d_in[4];
  const float* bgi    = (const float*)d_in[5];
  const float* Wgn    = (const float*)d_in[6];
  const float* bgn    = (const float*)d_in[7];
  const int*   row    = (const int*)d_in[8];
  const int*   col    = (const int*)d_in[9];
  float* out = (float*)d_out;

  const int N = in_sizes[0] / DU;
  const int E = in_sizes[1];
  const int NB = (N + 1023) / 1024;  // 49 for N=50000 (must be <= 64)

  // Workspace (~35.7 MB): all offsets 16B-aligned
  ushort* Xb    = (ushort*)d_ws;                  // N*96 bf16  (9.6 MB)
  ushort* newXb = Xb + (size_t)N * DU;            // 9.6 MB
  ushort* aggb  = newXb + (size_t)N * DU;         // 9.6 MB
  ushort* WTn   = aggb + (size_t)N * DU;          // 18 KB
  ushort* WTgi  = WTn + DU * DU;
  ushort* WTgn  = WTgi + DU * DU;
  int2*   epack = (int2*)(WTgn + DU * DU);        // 6.4 MB
  int*    hist   = (int*)(epack + E);             // N
  int*    cursor = hist + N;                      // N
  int*    bsum   = cursor + N;                    // 64

  hipMemsetAsync(hist, 0, (size_t)N * sizeof(int), stream);

  k_prep <<<1024, 256, 0, stream>>>(X, Wn, Wgi, Wgn, row, Xb, WTn, WTgi, WTgn, hist, N, E);
  k_scan1<<<NB, 256, 0, stream>>>(hist, cursor, bsum, N);
  k_scan3<<<NB, 256, 0, stream>>>(cursor, bsum, N);
  k_fill <<<768, 256, 0, stream>>>(row, col, a_vals, cursor, epack, E, N);
  k_newXM<<<(N + 63) / 64, 256, 0, stream>>>(Xb, WTn, bn, newXb, N);
  k_agg  <<<((size_t)N * DU4 + 255) / 256, 256, 0, stream>>>(newXb, cursor, epack, aggb, N);
  k_gateM<<<(N + 63) / 64, 256, 0, stream>>>(Xb, aggb, WTgi, WTgn, bgi, bgn, X, out, N);
}